// Round 12
// baseline (151.523 us; speedup 1.0000x reference)
//
#include <hip/hip_runtime.h>
#include <hip/hip_bf16.h>
#include <math.h>

constexpr int B = 64, S = 512, D = 768, H1 = 256, H2 = 128;
constexpr float THR = 0.1f;

typedef short bf16x8 __attribute__((ext_vector_type(8)));
typedef float f32x4 __attribute__((ext_vector_type(4)));
typedef unsigned int uint_t;
typedef const __attribute__((address_space(1))) unsigned int* gptr_t;
typedef __attribute__((address_space(3))) unsigned int* lptr_t;

__device__ __forceinline__ unsigned short f2bf(float f) {
    unsigned int u = __builtin_bit_cast(unsigned int, f);
    unsigned int r = (u + 0x7FFFu + ((u >> 16) & 1u)) >> 16;
    return (unsigned short)r;
}
__device__ __forceinline__ float bf2f(unsigned short b) {
    return __builtin_bit_cast(float, (unsigned int)b << 16);
}
// fp8 e4m3fn encode (input guaranteed positive, in normal range)
__device__ __forceinline__ unsigned char f2fp8(float f) {
    uint_t u = __builtin_bit_cast(uint_t, f);
    u += 0x7FFFFu + ((u >> 20) & 1u);      // RNE to 3-bit mantissa
    return (unsigned char)((((u >> 23) - 120u) << 3) | ((u >> 20) & 7u));
}
__device__ __forceinline__ float fp82f(unsigned char q) {
    uint_t e = (q >> 3) & 0xFu, m = q & 7u;
    if (e == 0) return (float)m * 0.001953125f;   // denormal: m * 2^-9
    return __builtin_bit_cast(float, ((e + 120u) << 23) | (m << 20));
}
__device__ __forceinline__ void gl2lds16(const void* g, void* l) {
    __builtin_amdgcn_global_load_lds((gptr_t)g, (lptr_t)l, 16, 0, 0);
}
__device__ __forceinline__ uint4 pack8(const float4& a, const float4& b) {
    uint4 o;
    o.x = (uint_t)f2bf(a.x) | ((uint_t)f2bf(a.y) << 16);
    o.y = (uint_t)f2bf(a.z) | ((uint_t)f2bf(a.w) << 16);
    o.z = (uint_t)f2bf(b.x) | ((uint_t)f2bf(b.y) << 16);
    o.w = (uint_t)f2bf(b.z) | ((uint_t)f2bf(b.w) << 16);
    return o;
}

// ------- tiny prologue: zero accumulators, transpose-cast W1/W2 -----------------
__global__ __launch_bounds__(256) void k_cast(const float* __restrict__ W1,
                                              short* __restrict__ W1T,
                                              const float* __restrict__ W2,
                                              short* __restrict__ W2T,
                                              float* __restrict__ zbuf) {
    const int id = blockIdx.x * 256 + threadIdx.x;
    if (id < 18432) ((float4*)zbuf)[id] = make_float4(0.f, 0.f, 0.f, 0.f);
    if (id < 196608) {                       // W1T[n][k] = W1[k][n]
        const int n = id / D, k = id - n * D;
        W1T[id] = (short)f2bf(W1[(size_t)k * H1 + n]);
    } else if (id < 229376) {                // W2T[n][k] = W2[k][n]
        const int i2 = id - 196608;
        const int n = i2 / H1, k = i2 - n * H1;
        W2T[i2] = (short)f2bf(W2[(size_t)k * H2 + n]);
    }
}

// ------- logits: fp32-H reg-staged cast + expL(fp8) + row sums ------------------
// Diagonal tiles (bi==bj) stage only As (As==Bs) and write the bf16 H panel to
// Hb global (each batch's 4 diagonal tiles cover all rows exactly once).
__global__ __launch_bounds__(256) void k_logits(const float* __restrict__ H,
                                                short* __restrict__ HbW,
                                                unsigned char* __restrict__ L8,
                                                float* __restrict__ rsum) {
    const int orig = blockIdx.x;
    const int wg = (orig & 7) * 128 + (orig >> 3);   // 8 XCDs x 8 batches each
    const int bz = wg >> 4;
    const int bi = (wg >> 2) & 3, bj = wg & 3;
    const bool diag = (bi == bj);
    const float* Hf = H + (size_t)bz * S * D;
    short* Hw = HbW + (size_t)bz * S * D;
    unsigned char* Lb = L8 + (size_t)bz * S * S;
    float* rs = rsum + bz * S;
    const int M0 = bi * 128, N0 = bj * 128;

    __shared__ __align__(16) short As[8192];
    __shared__ __align__(16) short Bs[8192];

    const int tid = threadIdx.x, lane = tid & 63, wid = tid >> 6;
    const int wm = (wid & 1) * 64, wn = (wid >> 1) * 64;
    const int r_in = lane >> 3, kc = lane & 7;

    f32x4 zero = {0.f, 0.f, 0.f, 0.f};
    f32x4 acc[4][4];
    #pragma unroll
    for (int mi = 0; mi < 4; ++mi)
        #pragma unroll
        for (int nj = 0; nj < 4; ++nj) acc[mi][nj] = zero;

    const short* Bsrc = diag ? As : Bs;

    for (int t = 0; t < 12; ++t) {
        const int col = t * 64 + ((kc ^ r_in) << 3);
        #pragma unroll
        for (int q = 0; q < 4; ++q) {
            const int ch = wid * 4 + q;
            const int row = M0 + ch * 8 + r_in;
            const float4 a = *(const float4*)&Hf[(size_t)row * D + col];
            const float4 b = *(const float4*)&Hf[(size_t)row * D + col + 4];
            const uint4 o = pack8(a, b);
            *(uint4*)&As[ch * 512 + lane * 8] = o;
            if (diag) *(uint4*)&Hw[(size_t)row * D + col] = o;
        }
        if (!diag) {
            #pragma unroll
            for (int q = 0; q < 4; ++q) {
                const int ch = wid * 4 + q;
                const int row = N0 + ch * 8 + r_in;
                const float4 a = *(const float4*)&Hf[(size_t)row * D + col];
                const float4 b = *(const float4*)&Hf[(size_t)row * D + col + 4];
                *(uint4*)&Bs[ch * 512 + lane * 8] = pack8(a, b);
            }
        }
        __syncthreads();
        #pragma unroll
        for (int kk = 0; kk < 2; ++kk) {
            bf16x8 af[4], bfr[4];
            const int g0 = kk * 4 + (lane >> 4);
            #pragma unroll
            for (int mi = 0; mi < 4; ++mi) {
                const int row = wm + mi * 16 + (lane & 15);
                af[mi] = *(const bf16x8*)&As[row * 64 + ((g0 ^ (row & 7)) << 3)];
            }
            #pragma unroll
            for (int nj = 0; nj < 4; ++nj) {
                const int row = wn + nj * 16 + (lane & 15);
                bfr[nj] = *(const bf16x8*)&Bsrc[row * 64 + ((g0 ^ (row & 7)) << 3)];
            }
            #pragma unroll
            for (int mi = 0; mi < 4; ++mi)
                #pragma unroll
                for (int nj = 0; nj < 4; ++nj)
                    acc[mi][nj] = __builtin_amdgcn_mfma_f32_16x16x32_bf16(
                        af[mi], bfr[nj], acc[mi][nj], 0, 0, 0);
        }
        __syncthreads();
    }

    #pragma unroll
    for (int mi = 0; mi < 4; ++mi)
        #pragma unroll
        for (int nj = 0; nj < 4; ++nj) {
            f32x4 v = acc[mi][nj];
            acc[mi][nj][0] = __expf(v[0]);
            acc[mi][nj][1] = __expf(v[1]);
            acc[mi][nj][2] = __expf(v[2]);
            acc[mi][nj][3] = __expf(v[3]);
        }

    #pragma unroll
    for (int mi = 0; mi < 4; ++mi) {
        const int mb = wm + mi * 16 + (lane >> 4) * 4;
        #pragma unroll
        for (int nj = 0; nj < 4; ++nj) {
            const int n = wn + nj * 16 + (lane & 15);
            f32x4 v = acc[mi][nj];
            uchar4 o;
            o.x = f2fp8(v[0]); o.y = f2fp8(v[1]);
            o.z = f2fp8(v[2]); o.w = f2fp8(v[3]);
            *(uchar4*)&Lb[(size_t)(N0 + n) * S + M0 + mb] = o;
        }
    }

    #pragma unroll
    for (int mi = 0; mi < 4; ++mi)
        #pragma unroll
        for (int r = 0; r < 4; ++r) {
            float s = acc[mi][0][r] + acc[mi][1][r] + acc[mi][2][r] + acc[mi][3][r];
            s += __shfl_xor(s, 1); s += __shfl_xor(s, 2);
            s += __shfl_xor(s, 4); s += __shfl_xor(s, 8);
            if ((lane & 15) == 0)
                atomicAdd(&rs[M0 + wm + mi * 16 + (lane >> 4) * 4 + r], s);
        }
}

// ------- fused: prep (8/9 of blocks) + xw1 NT-GEMM (1/9 of blocks) --------------
__global__ __launch_bounds__(256) void k_prep_gemm(
    const unsigned char* __restrict__ L8, const float* __restrict__ rsum,
    const int* __restrict__ mask, float* __restrict__ dis,
    float* __restrict__ wacc, uint_t* __restrict__ ents, uint_t* __restrict__ cnts,
    const short* __restrict__ W1T, const short* __restrict__ Hb,
    short* __restrict__ xw1) {
    __shared__ __align__(16) short As[128 * 64];   // used by gemm branch only
    __shared__ __align__(16) short Bs[64 * 64];

    const int blk = blockIdx.x;
    const int r9 = blk % 9;
    const int tid = threadIdx.x, lane = tid & 63, wid = tid >> 6;

    if (r9 != 8) {
        // ---------------- prep path ----------------
        const int p = (blk / 9) * 8 + r9;            // 0..8191
        const int j = p * 4 + (tid >> 6);            // b*S + jl
        const int b = j >> 9, jl = j & (S - 1);
        const size_t base = (size_t)b * S * S + (size_t)jl * S + lane * 8;
        const uint2 r = *(const uint2*)(L8 + base);
        const int i0 = lane * 8;
        const float4 sa = *(const float4*)&rsum[b * S + i0];
        const float4 sb = *(const float4*)&rsum[b * S + i0 + 4];
        const float rsv[8] = {sa.x, sa.y, sa.z, sa.w, sb.x, sb.y, sb.z, sb.w};
        float a[8];
        float deg = 0.f;
        #pragma unroll
        for (int e = 0; e < 8; ++e) {
            const unsigned char q = (e < 4) ? (unsigned char)(r.x >> (e * 8))
                                            : (unsigned char)(r.y >> ((e - 4) * 8));
            float att = fp82f(q) / rsv[e];           // att[i][j], i = i0+e
            if (i0 + e == jl) a[e] = (att > THR) ? att : 1.0f;
            else              a[e] = (att > THR) ? att : 0.0f;
            deg += a[e];
        }
        #pragma unroll
        for (int off = 1; off < 64; off <<= 1) deg += __shfl_xor(deg, off);
        const float d = (deg > 0.f) ? rsqrtf(deg) : 0.f;
        const float cv = d * (float)mask[j];
        if (lane == 0) dis[j] = d;
        #pragma unroll
        for (int e = 0; e < 8; ++e)
            if (a[e] != 0.f) atomicAdd(&wacc[b * S + i0 + e], cv * a[e]);

        unsigned long long bl[8];
        #pragma unroll
        for (int e = 0; e < 8; ++e) bl[e] = __ballot(a[e] != 0.f);
        const unsigned long long lt = (lane == 0) ? 0ull : (~0ull >> (64 - lane));
        int pre = 0, tot = 0;
        #pragma unroll
        for (int e = 0; e < 8; ++e) {
            pre += __popcll(bl[e] & lt);
            tot += __popcll(bl[e]);
        }
        uint_t* rowents = ents + (size_t)j * S;
        int own = 0;
        #pragma unroll
        for (int e = 0; e < 8; ++e) {
            if (a[e] != 0.f) {
                rowents[pre + own] = ((uint_t)(i0 + e) << 16) | (uint_t)f2bf(a[e]);
                ++own;
            }
        }
        if (lane == 0) cnts[j] = (uint_t)tot;
        return;
    }

    // ---------------- gemm path (xw1, unscaled) ----------------
    const int orig = blk / 9;                        // 0..1023
    const int wg = (orig & 7) * 128 + (orig >> 3);   // XCD-contiguous chunks
    const int bx = wg & 1, by = wg >> 1;
    const int M0 = bx * 128, N0 = by * 64;

    const int wm = (wid & 1) * 64, wn = (wid >> 1) * 32;
    const int r_in = lane >> 3, kc = lane & 7;
    const int kswz = ((kc ^ r_in) << 3);

    f32x4 zero = {0.f, 0.f, 0.f, 0.f};
    f32x4 acc[4][2];
    #pragma unroll
    for (int mi = 0; mi < 4; ++mi) {
        acc[mi][0] = zero; acc[mi][1] = zero;
    }

    for (int t = 0; t < 12; ++t) {
        const int kt = t << 6;
        #pragma unroll
        for (int q = 0; q < 4; ++q) {
            const int ch = wid * 4 + q;
            gl2lds16(W1T + (size_t)(M0 + ch * 8 + r_in) * D + kt + kswz, &As[ch * 512]);
        }
        #pragma unroll
        for (int q = 0; q < 2; ++q) {
            const int ch = wid * 2 + q;
            gl2lds16(Hb + (size_t)(N0 + ch * 8 + r_in) * D + kt + kswz, &Bs[ch * 512]);
        }
        __syncthreads();
        #pragma unroll
        for (int kk = 0; kk < 2; ++kk) {
            bf16x8 af[4], bfr[2];
            const int g0 = kk * 4 + (lane >> 4);
            #pragma unroll
            for (int mi = 0; mi < 4; ++mi) {
                const int row = wm + mi * 16 + (lane & 15);
                af[mi] = *(const bf16x8*)&As[row * 64 + ((g0 ^ (row & 7)) << 3)];
            }
            #pragma unroll
            for (int nj = 0; nj < 2; ++nj) {
                const int row = wn + nj * 16 + (lane & 15);
                bfr[nj] = *(const bf16x8*)&Bs[row * 64 + ((g0 ^ (row & 7)) << 3)];
            }
            #pragma unroll
            for (int mi = 0; mi < 4; ++mi)
                #pragma unroll
                for (int nj = 0; nj < 2; ++nj)
                    acc[mi][nj] = __builtin_amdgcn_mfma_f32_16x16x32_bf16(
                        af[mi], bfr[nj], acc[mi][nj], 0, 0, 0);
        }
        __syncthreads();
    }

    #pragma unroll
    for (int mi = 0; mi < 4; ++mi) {
        const int m = M0 + wm + mi * 16 + (lane >> 4) * 4;
        #pragma unroll
        for (int nj = 0; nj < 2; ++nj) {
            const int n = N0 + wn + nj * 16 + (lane & 15);
            f32x4 v = acc[mi][nj];
            ushort4 o = make_ushort4(f2bf(v[0]), f2bf(v[1]), f2bf(v[2]), f2bf(v[3]));
            *(ushort4*)&xw1[(size_t)n * H1 + m] = o;
        }
    }
}

// ---------------- sparse aggregation via CSR: y1[j][h], 8 rows per block --------
__global__ __launch_bounds__(256) void k_agg(const uint_t* __restrict__ ents,
                                             const uint_t* __restrict__ cnts,
                                             const float* __restrict__ dis,
                                             const short* __restrict__ xw1,
                                             const float* __restrict__ b1,
                                             short* __restrict__ y1) {
    const int tid = threadIdx.x;
    const int h = tid;
    const float bias = b1[h];
    __shared__ uint_t sents[S];
    for (int jj = 0; jj < 8; ++jj) {
        const int j = blockIdx.x * 8 + jj;
        const int b = j >> 9;
        const int cnt = (int)cnts[j];
        for (int k = tid; k < cnt; k += 256) sents[k] = ents[(size_t)j * S + k];
        __syncthreads();
        float acc = 0.f;
        for (int k = 0; k < cnt; ++k) {
            const uint_t p = sents[k];
            const int i = (int)(p >> 16);
            const float val = bf2f((unsigned short)(p & 0xFFFFu)) * dis[b * S + i];
            acc += val * bf2f((unsigned short)xw1[(size_t)(b * S + i) * H1 + h]);
        }
        const float o = fmaxf(dis[j] * acc + bias, 0.f);
        y1[(size_t)j * H1 + h] = (short)f2bf(o);
        __syncthreads();
    }
}

// ------- xw2 NT-GEMM with fused emb reduction (128 x 64 tile) -------------------
__global__ __launch_bounds__(256) void k_gemm_emb(
    const short* __restrict__ W2T, const short* __restrict__ y1,
    const float* __restrict__ wacc, const float* __restrict__ dis,
    float* __restrict__ embp) {
    const int orig = blockIdx.x;
    const int wg = (orig & 7) * 64 + (orig >> 3);
    const int N0 = wg * 64;          // token tile; M0 = 0 (H2=128 single M tile)

    __shared__ __align__(16) short As[128 * 64];
    __shared__ __align__(16) short Bs[64 * 64];

    const int tid = threadIdx.x, lane = tid & 63, wid = tid >> 6;
    const int wm = (wid & 1) * 64, wn = (wid >> 1) * 32;
    const int r_in = lane >> 3, kc = lane & 7;
    const int kswz = ((kc ^ r_in) << 3);

    f32x4 zero = {0.f, 0.f, 0.f, 0.f};
    f32x4 acc[4][2];
    #pragma unroll
    for (int mi = 0; mi < 4; ++mi) {
        acc[mi][0] = zero; acc[mi][1] = zero;
    }

    for (int t = 0; t < 4; ++t) {
        const int kt = t << 6;
        #pragma unroll
        for (int q = 0; q < 4; ++q) {
            const int ch = wid * 4 + q;
            gl2lds16(W2T + (size_t)(ch * 8 + r_in) * H1 + kt + kswz, &As[ch * 512]);
        }
        #pragma unroll
        for (int q = 0; q < 2; ++q) {
            const int ch = wid * 2 + q;
            gl2lds16(y1 + (size_t)(N0 + ch * 8 + r_in) * H1 + kt + kswz, &Bs[ch * 512]);
        }
        __syncthreads();
        #pragma unroll
        for (int kk = 0; kk < 2; ++kk) {
            bf16x8 af[4], bfr[2];
            const int g0 = kk * 4 + (lane >> 4);
            #pragma unroll
            for (int mi = 0; mi < 4; ++mi) {
                const int row = wm + mi * 16 + (lane & 15);
                af[mi] = *(const bf16x8*)&As[row * 64 + ((g0 ^ (row & 7)) << 3)];
            }
            #pragma unroll
            for (int nj = 0; nj < 2; ++nj) {
                const int row = wn + nj * 16 + (lane & 15);
                bfr[nj] = *(const bf16x8*)&Bs[row * 64 + ((g0 ^ (row & 7)) << 3)];
            }
            #pragma unroll
            for (int mi = 0; mi < 4; ++mi)
                #pragma unroll
                for (int nj = 0; nj < 2; ++nj)
                    acc[mi][nj] = __builtin_amdgcn_mfma_f32_16x16x32_bf16(
                        af[mi], bfr[nj], acc[mi][nj], 0, 0, 0);
        }
        __syncthreads();
    }

    const int bb = N0 >> 9;
    float wv[2];
    #pragma unroll
    for (int nj = 0; nj < 2; ++nj) {
        const int gn = N0 + wn + nj * 16 + (lane & 15);
        wv[nj] = wacc[gn] * dis[gn];
    }
    #pragma unroll
    for (int mi = 0; mi < 4; ++mi)
        #pragma unroll
        for (int r = 0; r < 4; ++r) {
            float s = acc[mi][0][r] * wv[0] + acc[mi][1][r] * wv[1];
            s += __shfl_xor(s, 1); s += __shfl_xor(s, 2);
            s += __shfl_xor(s, 4); s += __shfl_xor(s, 8);
            if ((lane & 15) == 0) {
                const int h = wm + mi * 16 + (lane >> 4) * 4 + r;
                atomicAdd(&embp[bb * H2 + h], s);
            }
        }
}

// ---------------- final: head from emb[64][128] ---------------------------------
__global__ __launch_bounds__(128) void k_final(const float* __restrict__ emb,
                                               const int* __restrict__ mask,
                                               const float* __restrict__ b2,
                                               const float* __restrict__ Wc,
                                               const float* __restrict__ bc,
                                               float* __restrict__ out) {
    const int b = blockIdx.x;
    const int h = threadIdx.x;
    const int* mb = mask + b * S;

    float msum = 0.f;
    for (int i = h; i < S; i += 128) msum += (float)mb[i];
    #pragma unroll
    for (int off = 1; off < 64; off <<= 1) msum += __shfl_xor(msum, off);
    __shared__ float redm[2], redv[2];
    if ((h & 63) == 0) redm[h >> 6] = msum;
    __syncthreads();
    msum = redm[0] + redm[1];

    const float e = b2[h] + emb[b * H2 + h] / msum;
    float val = e * Wc[h];
    #pragma unroll
    for (int off = 1; off < 64; off <<= 1) val += __shfl_xor(val, off);
    if ((h & 63) == 0) redv[h >> 6] = val;
    __syncthreads();
    if (h == 0) {
        float z = redv[0] + redv[1] + bc[0];
        out[b] = 1.f / (1.f + expf(-z));
    }
}

extern "C" void kernel_launch(void* const* d_in, const int* in_sizes, int n_in,
                              void* d_out, int out_size, void* d_ws, size_t ws_size,
                              hipStream_t stream) {
    const float* H    = (const float*)d_in[0];
    const int*   mask = (const int*)d_in[1];
    const float* W1   = (const float*)d_in[2];
    const float* b1   = (const float*)d_in[3];
    const float* W2   = (const float*)d_in[4];
    const float* b2   = (const float*)d_in[5];
    const float* Wc   = (const float*)d_in[6];
    const float* bc   = (const float*)d_in[7];
    float* out = (float*)d_out;

    const int NTOK = B * S;  // 32768

    // workspace layout (bytes)
    char* wsb = (char*)d_ws;
    short* Hb    = (short*)(wsb);                       // 48 MB bf16 (written by k_logits)
    short* y1    = (short*)(wsb);                       // overlays Hb (dead by then)
    unsigned char* Lbuf = (unsigned char*)(wsb + 50331648);  // 16 MB fp8
    short* xw1   = (short*)(wsb + 83886080);            // 16 MB, [tok][H1]
    float* rsum  = (float*)(wsb + 109051904);           // 32768 f
    float* wacc  = rsum + NTOK;                         // 32768 f
    float* emb   = wacc + NTOK;                         // 8192 f (zeroed with rsum/wacc)
    float* dis   = emb + 8192;                          // 32768 f
    short* W1T   = (short*)(dis + NTOK);                // 196608 el
    short* W2T   = W1T + 196608;                        // 32768 el
    uint_t* ents = (uint_t*)(wsb + 134217728);          // 64 MB
    uint_t* cnts = (uint_t*)(wsb + 201326592);          // 32768 u32

    // prologue: zero rsum+wacc+emb, cast weights (transposed)
    k_cast<<<1024, 256, 0, stream>>>(W1, W1T, W2, W2T, rsum);

    // expL fp8 + row sums; casts H->bf16 on the fly, diagonal tiles emit Hb
    k_logits<<<1024, 256, 0, stream>>>(H, Hb, Lbuf, rsum);

    // fused: prep (deg/dis/wacc/CSR) interleaved with UNSCALED xw1 GEMM
    k_prep_gemm<<<9216, 256, 0, stream>>>(Lbuf, rsum, mask, dis, wacc, ents, cnts,
                                          W1T, Hb, xw1);

    // sparse aggregation + relu + bias (CSR-driven, dis_i applied per entry)
    k_agg<<<4096, 256, 0, stream>>>(ents, cnts, dis, xw1, b1, y1);

    // emb[b][h2] += sum_t (y1 @ W2)[t][h2] * wacc[t]*dis[t]
    k_gemm_emb<<<512, 256, 0, stream>>>(W2T, y1, wacc, dis, emb);

    k_final<<<B, 128, 0, stream>>>(emb, mask, b2, Wc, bc, out);
}

// Round 13
// 145.154 us; speedup vs baseline: 1.0439x; 1.0439x over previous
//
#include <hip/hip_runtime.h>
#include <hip/hip_bf16.h>
#include <math.h>

constexpr int B = 64, S = 512, D = 768, H1 = 256, H2 = 128;
constexpr float THR = 0.1f;

typedef short bf16x8 __attribute__((ext_vector_type(8)));
typedef float f32x4 __attribute__((ext_vector_type(4)));
typedef unsigned int uint_t;
typedef const __attribute__((address_space(1))) unsigned int* gptr_t;
typedef __attribute__((address_space(3))) unsigned int* lptr_t;

__device__ __forceinline__ unsigned short f2bf(float f) {
    unsigned int u = __builtin_bit_cast(unsigned int, f);
    unsigned int r = (u + 0x7FFFu + ((u >> 16) & 1u)) >> 16;
    return (unsigned short)r;
}
__device__ __forceinline__ float bf2f(unsigned short b) {
    return __builtin_bit_cast(float, (unsigned int)b << 16);
}
// fp8 e4m3fn encode (input guaranteed positive, in normal range)
__device__ __forceinline__ unsigned char f2fp8(float f) {
    uint_t u = __builtin_bit_cast(uint_t, f);
    u += 0x7FFFFu + ((u >> 20) & 1u);      // RNE to 3-bit mantissa
    return (unsigned char)((((u >> 23) - 120u) << 3) | ((u >> 20) & 7u));
}
__device__ __forceinline__ float fp82f(unsigned char q) {
    uint_t e = (q >> 3) & 0xFu, m = q & 7u;
    if (e == 0) return (float)m * 0.001953125f;   // denormal: m * 2^-9
    return __builtin_bit_cast(float, ((e + 120u) << 23) | (m << 20));
}
__device__ __forceinline__ void gl2lds16(const void* g, void* l) {
    __builtin_amdgcn_global_load_lds((gptr_t)g, (lptr_t)l, 16, 0, 0);
}

// ------- fused prologue: zero accumulators, transpose-cast W1/W2, cast H --------
__global__ __launch_bounds__(256) void k_cast(const float* __restrict__ in,
                                              short* __restrict__ out,
                                              const float* __restrict__ W1,
                                              short* __restrict__ W1T,
                                              const float* __restrict__ W2,
                                              short* __restrict__ W2T,
                                              float* __restrict__ zbuf) {
    const int id = blockIdx.x * 256 + threadIdx.x;
    if (id < 18432) ((float4*)zbuf)[id] = make_float4(0.f, 0.f, 0.f, 0.f);
    if (id < 196608) {                       // W1T[n][k] = W1[k][n]
        const int n = id / D, k = id - n * D;
        W1T[id] = (short)f2bf(W1[(size_t)k * H1 + n]);
    } else if (id < 229376) {                // W2T[n][k] = W2[k][n]
        const int i2 = id - 196608;
        const int n = i2 / H1, k = i2 - n * H1;
        W2T[i2] = (short)f2bf(W2[(size_t)k * H2 + n]);
    }
    for (int i = id; i < 3145728; i += 524288) {
        float4 a = ((const float4*)in)[i * 2];
        float4 b = ((const float4*)in)[i * 2 + 1];
        uint4 o;
        o.x = (uint_t)f2bf(a.x) | ((uint_t)f2bf(a.y) << 16);
        o.y = (uint_t)f2bf(a.z) | ((uint_t)f2bf(a.w) << 16);
        o.z = (uint_t)f2bf(b.x) | ((uint_t)f2bf(b.y) << 16);
        o.w = (uint_t)f2bf(b.z) | ((uint_t)f2bf(b.w) << 16);
        ((uint4*)out)[i] = o;
    }
}

// ---------------- logits: expL (fp8) + atomic f32 row-sums ----------------------
__global__ __launch_bounds__(256) void k_logits(const short* __restrict__ Hb_,
                                                unsigned char* __restrict__ L8,
                                                float* __restrict__ rsum) {
    const int orig = blockIdx.x;
    const int wg = (orig & 7) * 128 + (orig >> 3);
    const int bz = wg >> 4;
    const int bi = (wg >> 2) & 3, bj = wg & 3;
    const short* Ab = Hb_ + (size_t)bz * S * D;
    unsigned char* Lb = L8 + (size_t)bz * S * S;
    float* rs = rsum + bz * S;
    const int M0 = bi * 128, N0 = bj * 128;

    __shared__ __align__(16) short As[8192];
    __shared__ __align__(16) short Bs[8192];

    const int tid = threadIdx.x, lane = tid & 63, wid = tid >> 6;
    const int wm = (wid & 1) * 64, wn = (wid >> 1) * 64;
    const int r_in = lane >> 3, kc = lane & 7;
    const int kswz = ((kc ^ r_in) << 3);

    f32x4 zero = {0.f, 0.f, 0.f, 0.f};
    f32x4 acc[4][4];
    #pragma unroll
    for (int mi = 0; mi < 4; ++mi)
        #pragma unroll
        for (int nj = 0; nj < 4; ++nj) acc[mi][nj] = zero;

    for (int t = 0; t < 12; ++t) {
        const int kt = t * 64;
        #pragma unroll
        for (int q = 0; q < 4; ++q) {
            const int ch = wid * 4 + q;
            gl2lds16(Ab + (size_t)(M0 + ch * 8 + r_in) * D + kt + kswz, &As[ch * 512]);
        }
        #pragma unroll
        for (int q = 0; q < 4; ++q) {
            const int ch = wid * 4 + q;
            gl2lds16(Ab + (size_t)(N0 + ch * 8 + r_in) * D + kt + kswz, &Bs[ch * 512]);
        }
        __syncthreads();
        #pragma unroll
        for (int kk = 0; kk < 2; ++kk) {
            bf16x8 af[4], bfr[4];
            const int g0 = kk * 4 + (lane >> 4);
            #pragma unroll
            for (int mi = 0; mi < 4; ++mi) {
                const int row = wm + mi * 16 + (lane & 15);
                af[mi] = *(const bf16x8*)&As[row * 64 + ((g0 ^ (row & 7)) << 3)];
            }
            #pragma unroll
            for (int nj = 0; nj < 4; ++nj) {
                const int row = wn + nj * 16 + (lane & 15);
                bfr[nj] = *(const bf16x8*)&Bs[row * 64 + ((g0 ^ (row & 7)) << 3)];
            }
            #pragma unroll
            for (int mi = 0; mi < 4; ++mi)
                #pragma unroll
                for (int nj = 0; nj < 4; ++nj)
                    acc[mi][nj] = __builtin_amdgcn_mfma_f32_16x16x32_bf16(
                        af[mi], bfr[nj], acc[mi][nj], 0, 0, 0);
        }
        __syncthreads();
    }

    #pragma unroll
    for (int mi = 0; mi < 4; ++mi)
        #pragma unroll
        for (int nj = 0; nj < 4; ++nj) {
            f32x4 v = acc[mi][nj];
            acc[mi][nj][0] = __expf(v[0]);
            acc[mi][nj][1] = __expf(v[1]);
            acc[mi][nj][2] = __expf(v[2]);
            acc[mi][nj][3] = __expf(v[3]);
        }

    #pragma unroll
    for (int mi = 0; mi < 4; ++mi) {
        const int mb = wm + mi * 16 + (lane >> 4) * 4;
        #pragma unroll
        for (int nj = 0; nj < 4; ++nj) {
            const int n = wn + nj * 16 + (lane & 15);
            f32x4 v = acc[mi][nj];
            uchar4 o;
            o.x = f2fp8(v[0]); o.y = f2fp8(v[1]);
            o.z = f2fp8(v[2]); o.w = f2fp8(v[3]);
            *(uchar4*)&Lb[(size_t)(N0 + n) * S + M0 + mb] = o;
        }
    }

    #pragma unroll
    for (int mi = 0; mi < 4; ++mi)
        #pragma unroll
        for (int r = 0; r < 4; ++r) {
            float s = acc[mi][0][r] + acc[mi][1][r] + acc[mi][2][r] + acc[mi][3][r];
            s += __shfl_xor(s, 1); s += __shfl_xor(s, 2);
            s += __shfl_xor(s, 4); s += __shfl_xor(s, 8);
            if ((lane & 15) == 0)
                atomicAdd(&rs[M0 + wm + mi * 16 + (lane >> 4) * 4 + r], s);
        }
}

// ------- fused: prep (8/9 of blocks) + xw1 NT-GEMM (1/9 of blocks) --------------
__global__ __launch_bounds__(256) void k_prep_gemm(
    const unsigned char* __restrict__ L8, const float* __restrict__ rsum,
    const int* __restrict__ mask, float* __restrict__ dis,
    float* __restrict__ wacc, uint_t* __restrict__ ents, uint_t* __restrict__ cnts,
    const short* __restrict__ W1T, const short* __restrict__ Hb,
    short* __restrict__ xw1) {
    __shared__ __align__(16) short As[128 * 64];   // used by gemm branch only
    __shared__ __align__(16) short Bs[64 * 64];

    const int blk = blockIdx.x;
    const int r9 = blk % 9;
    const int tid = threadIdx.x, lane = tid & 63, wid = tid >> 6;

    if (r9 != 8) {
        // ---------------- prep path ----------------
        const int p = (blk / 9) * 8 + r9;            // 0..8191
        const int j = p * 4 + (tid >> 6);            // b*S + jl
        const int b = j >> 9, jl = j & (S - 1);
        const size_t base = (size_t)b * S * S + (size_t)jl * S + lane * 8;
        const uint2 r = *(const uint2*)(L8 + base);
        const int i0 = lane * 8;
        const float4 sa = *(const float4*)&rsum[b * S + i0];
        const float4 sb = *(const float4*)&rsum[b * S + i0 + 4];
        const float rsv[8] = {sa.x, sa.y, sa.z, sa.w, sb.x, sb.y, sb.z, sb.w};
        float a[8];
        float deg = 0.f;
        #pragma unroll
        for (int e = 0; e < 8; ++e) {
            const unsigned char q = (e < 4) ? (unsigned char)(r.x >> (e * 8))
                                            : (unsigned char)(r.y >> ((e - 4) * 8));
            float att = fp82f(q) / rsv[e];           // att[i][j], i = i0+e
            if (i0 + e == jl) a[e] = (att > THR) ? att : 1.0f;
            else              a[e] = (att > THR) ? att : 0.0f;
            deg += a[e];
        }
        #pragma unroll
        for (int off = 1; off < 64; off <<= 1) deg += __shfl_xor(deg, off);
        const float d = (deg > 0.f) ? rsqrtf(deg) : 0.f;
        const float cv = d * (float)mask[j];
        if (lane == 0) dis[j] = d;
        #pragma unroll
        for (int e = 0; e < 8; ++e)
            if (a[e] != 0.f) atomicAdd(&wacc[b * S + i0 + e], cv * a[e]);

        unsigned long long bl[8];
        #pragma unroll
        for (int e = 0; e < 8; ++e) bl[e] = __ballot(a[e] != 0.f);
        const unsigned long long lt = (lane == 0) ? 0ull : (~0ull >> (64 - lane));
        int pre = 0, tot = 0;
        #pragma unroll
        for (int e = 0; e < 8; ++e) {
            pre += __popcll(bl[e] & lt);
            tot += __popcll(bl[e]);
        }
        uint_t* rowents = ents + (size_t)j * S;
        int own = 0;
        #pragma unroll
        for (int e = 0; e < 8; ++e) {
            if (a[e] != 0.f) {
                rowents[pre + own] = ((uint_t)(i0 + e) << 16) | (uint_t)f2bf(a[e]);
                ++own;
            }
        }
        if (lane == 0) cnts[j] = (uint_t)tot;
        return;
    }

    // ---------------- gemm path (xw1, unscaled) ----------------
    const int orig = blk / 9;                        // 0..1023
    const int wg = (orig & 7) * 128 + (orig >> 3);   // XCD-contiguous chunks
    const int bx = wg & 1, by = wg >> 1;
    const int M0 = bx * 128, N0 = by * 64;

    const int wm = (wid & 1) * 64, wn = (wid >> 1) * 32;
    const int r_in = lane >> 3, kc = lane & 7;
    const int kswz = ((kc ^ r_in) << 3);

    f32x4 zero = {0.f, 0.f, 0.f, 0.f};
    f32x4 acc[4][2];
    #pragma unroll
    for (int mi = 0; mi < 4; ++mi) {
        acc[mi][0] = zero; acc[mi][1] = zero;
    }

    for (int t = 0; t < 12; ++t) {
        const int kt = t << 6;
        #pragma unroll
        for (int q = 0; q < 4; ++q) {
            const int ch = wid * 4 + q;
            gl2lds16(W1T + (size_t)(M0 + ch * 8 + r_in) * D + kt + kswz, &As[ch * 512]);
        }
        #pragma unroll
        for (int q = 0; q < 2; ++q) {
            const int ch = wid * 2 + q;
            gl2lds16(Hb + (size_t)(N0 + ch * 8 + r_in) * D + kt + kswz, &Bs[ch * 512]);
        }
        __syncthreads();
        #pragma unroll
        for (int kk = 0; kk < 2; ++kk) {
            bf16x8 af[4], bfr[2];
            const int g0 = kk * 4 + (lane >> 4);
            #pragma unroll
            for (int mi = 0; mi < 4; ++mi) {
                const int row = wm + mi * 16 + (lane & 15);
                af[mi] = *(const bf16x8*)&As[row * 64 + ((g0 ^ (row & 7)) << 3)];
            }
            #pragma unroll
            for (int nj = 0; nj < 2; ++nj) {
                const int row = wn + nj * 16 + (lane & 15);
                bfr[nj] = *(const bf16x8*)&Bs[row * 64 + ((g0 ^ (row & 7)) << 3)];
            }
            #pragma unroll
            for (int mi = 0; mi < 4; ++mi)
                #pragma unroll
                for (int nj = 0; nj < 2; ++nj)
                    acc[mi][nj] = __builtin_amdgcn_mfma_f32_16x16x32_bf16(
                        af[mi], bfr[nj], acc[mi][nj], 0, 0, 0);
        }
        __syncthreads();
    }

    #pragma unroll
    for (int mi = 0; mi < 4; ++mi) {
        const int m = M0 + wm + mi * 16 + (lane >> 4) * 4;
        #pragma unroll
        for (int nj = 0; nj < 2; ++nj) {
            const int n = N0 + wn + nj * 16 + (lane & 15);
            f32x4 v = acc[mi][nj];
            ushort4 o = make_ushort4(f2bf(v[0]), f2bf(v[1]), f2bf(v[2]), f2bf(v[3]));
            *(ushort4*)&xw1[(size_t)n * H1 + m] = o;
        }
    }
}

// ------- fused: CSR aggregation into LDS y1 + W2 GEMM + emb reduction -----------
// One block per 64-token tile. Phase 1: wave w builds y1 rows w*16..w*16+15 in
// LDS (barrier-free; entries broadcast via shfl). Phase 2: 128x64 NT-GEMM with
// B read from LDS (row pad 264 shorts -> 2-way bank conflicts = free).
__global__ __launch_bounds__(256) void k_agg_emb(
    const uint_t* __restrict__ ents, const uint_t* __restrict__ cnts,
    const float* __restrict__ dis, const float* __restrict__ wacc,
    const short* __restrict__ xw1, const float* __restrict__ b1,
    const short* __restrict__ W2T, float* __restrict__ embp) {
    constexpr int YP = 264;                       // padded y1 row (shorts)
    __shared__ __align__(16) short y1s[64 * YP];  // 33792 B
    __shared__ __align__(16) short As[128 * 64];  // 16 KB (W2T K-tile)

    const int orig = blockIdx.x;
    const int wg = (orig & 7) * 64 + (orig >> 3); // XCD swizzle, 512 wgs
    const int N0 = wg * 64;                       // global token base
    const int b = N0 >> 9;
    const int tid = threadIdx.x, lane = tid & 63, wid = tid >> 6;

    // ---- phase 1: y1 rows in LDS ----
    for (int u = 0; u < 16; ++u) {
        const int jj = wid * 16 + u;
        const int j = N0 + jj;
        const int cnt = (int)cnts[j];
        float acc0 = 0.f, acc1 = 0.f, acc2 = 0.f, acc3 = 0.f;
        for (int k0 = 0; k0 < cnt; k0 += 64) {
            uint_t my = 0;
            if (k0 + lane < cnt) my = ents[(size_t)j * S + k0 + lane];
            const int lim = (cnt - k0 < 64) ? (cnt - k0) : 64;
            for (int k = 0; k < lim; ++k) {
                const uint_t p = __shfl(my, k);
                const int i = (int)(p >> 16);
                const float val = bf2f((unsigned short)(p & 0xFFFFu)) * dis[b * S + i];
                const short* xr = &xw1[(size_t)(b * S + i) * H1];
                acc0 += val * bf2f((unsigned short)xr[lane]);
                acc1 += val * bf2f((unsigned short)xr[lane + 64]);
                acc2 += val * bf2f((unsigned short)xr[lane + 128]);
                acc3 += val * bf2f((unsigned short)xr[lane + 192]);
            }
        }
        const float dj = dis[j];
        y1s[jj * YP + lane      ] = (short)f2bf(fmaxf(dj * acc0 + b1[lane      ], 0.f));
        y1s[jj * YP + lane + 64 ] = (short)f2bf(fmaxf(dj * acc1 + b1[lane + 64 ], 0.f));
        y1s[jj * YP + lane + 128] = (short)f2bf(fmaxf(dj * acc2 + b1[lane + 128], 0.f));
        y1s[jj * YP + lane + 192] = (short)f2bf(fmaxf(dj * acc3 + b1[lane + 192], 0.f));
    }
    __syncthreads();

    // ---- phase 2: emb[b][h] += sum_t y1[t] @ W2 * wacc[t]*dis[t] ----
    const int wm = (wid & 1) * 64, wn = (wid >> 1) * 32;
    const int r_in = lane >> 3, kc = lane & 7;
    const int kswz = ((kc ^ r_in) << 3);

    f32x4 zero = {0.f, 0.f, 0.f, 0.f};
    f32x4 acc[4][2];
    #pragma unroll
    for (int mi = 0; mi < 4; ++mi) {
        acc[mi][0] = zero; acc[mi][1] = zero;
    }

    for (int t = 0; t < 4; ++t) {
        const int kt = t << 6;
        #pragma unroll
        for (int q = 0; q < 4; ++q) {
            const int ch = wid * 4 + q;
            gl2lds16(W2T + (size_t)(ch * 8 + r_in) * H1 + kt + kswz, &As[ch * 512]);
        }
        __syncthreads();
        #pragma unroll
        for (int kk = 0; kk < 2; ++kk) {
            bf16x8 af[4], bfr[2];
            const int g0 = kk * 4 + (lane >> 4);
            #pragma unroll
            for (int mi = 0; mi < 4; ++mi) {
                const int row = wm + mi * 16 + (lane & 15);
                af[mi] = *(const bf16x8*)&As[row * 64 + ((g0 ^ (row & 7)) << 3)];
            }
            #pragma unroll
            for (int nj = 0; nj < 2; ++nj) {
                const int tok = wn + nj * 16 + (lane & 15);
                const int col = kt + kk * 32 + (lane >> 4) * 8;
                bfr[nj] = *(const bf16x8*)&y1s[tok * YP + col];
            }
            #pragma unroll
            for (int mi = 0; mi < 4; ++mi)
                #pragma unroll
                for (int nj = 0; nj < 2; ++nj)
                    acc[mi][nj] = __builtin_amdgcn_mfma_f32_16x16x32_bf16(
                        af[mi], bfr[nj], acc[mi][nj], 0, 0, 0);
        }
        __syncthreads();
    }

    float wv[2];
    #pragma unroll
    for (int nj = 0; nj < 2; ++nj) {
        const int gn = N0 + wn + nj * 16 + (lane & 15);
        wv[nj] = wacc[gn] * dis[gn];
    }
    #pragma unroll
    for (int mi = 0; mi < 4; ++mi)
        #pragma unroll
        for (int r = 0; r < 4; ++r) {
            float s = acc[mi][0][r] * wv[0] + acc[mi][1][r] * wv[1];
            s += __shfl_xor(s, 1); s += __shfl_xor(s, 2);
            s += __shfl_xor(s, 4); s += __shfl_xor(s, 8);
            if ((lane & 15) == 0) {
                const int h = wm + mi * 16 + (lane >> 4) * 4 + r;
                atomicAdd(&embp[b * H2 + h], s);
            }
        }
}

// ---------------- final: head from emb[64][128] ---------------------------------
__global__ __launch_bounds__(128) void k_final(const float* __restrict__ emb,
                                               const int* __restrict__ mask,
                                               const float* __restrict__ b2,
                                               const float* __restrict__ Wc,
                                               const float* __restrict__ bc,
                                               float* __restrict__ out) {
    const int b = blockIdx.x;
    const int h = threadIdx.x;
    const int* mb = mask + b * S;

    float msum = 0.f;
    for (int i = h; i < S; i += 128) msum += (float)mb[i];
    #pragma unroll
    for (int off = 1; off < 64; off <<= 1) msum += __shfl_xor(msum, off);
    __shared__ float redm[2], redv[2];
    if ((h & 63) == 0) redm[h >> 6] = msum;
    __syncthreads();
    msum = redm[0] + redm[1];

    const float e = b2[h] + emb[b * H2 + h] / msum;
    float val = e * Wc[h];
    #pragma unroll
    for (int off = 1; off < 64; off <<= 1) val += __shfl_xor(val, off);
    if ((h & 63) == 0) redv[h >> 6] = val;
    __syncthreads();
    if (h == 0) {
        float z = redv[0] + redv[1] + bc[0];
        out[b] = 1.f / (1.f + expf(-z));
    }
}

extern "C" void kernel_launch(void* const* d_in, const int* in_sizes, int n_in,
                              void* d_out, int out_size, void* d_ws, size_t ws_size,
                              hipStream_t stream) {
    const float* H    = (const float*)d_in[0];
    const int*   mask = (const int*)d_in[1];
    const float* W1   = (const float*)d_in[2];
    const float* b1   = (const float*)d_in[3];
    const float* W2   = (const float*)d_in[4];
    const float* b2   = (const float*)d_in[5];
    const float* Wc   = (const float*)d_in[6];
    const float* bc   = (const float*)d_in[7];
    float* out = (float*)d_out;

    const int NTOK = B * S;  // 32768

    // workspace layout (bytes)
    char* wsb = (char*)d_ws;
    short* Hb    = (short*)(wsb);                       // 48 MB
    unsigned char* Lbuf = (unsigned char*)(wsb + 50331648);  // 16 MB fp8
    short* xw1   = (short*)(wsb + 83886080);            // 16 MB, [tok][H1]
    float* rsum  = (float*)(wsb + 109051904);           // 32768 f
    float* wacc  = rsum + NTOK;                         // 32768 f
    float* emb   = wacc + NTOK;                         // 8192 f (zeroed with rsum/wacc)
    float* dis   = emb + 8192;                          // 32768 f
    short* W1T   = (short*)(dis + NTOK);                // 196608 el
    short* W2T   = W1T + 196608;                        // 32768 el
    uint_t* ents = (uint_t*)(wsb + 134217728);          // 64 MB
    uint_t* cnts = (uint_t*)(wsb + 201326592);          // 32768 u32

    // prologue: zero rsum+wacc+emb, cast weights (transposed), cast H
    k_cast<<<2048, 256, 0, stream>>>(H, Hb, W1, W1T, W2, W2T, rsum);

    // expL fp8 (full grid, XCD swizzle, swizzled LDS) + row sums
    k_logits<<<1024, 256, 0, stream>>>(Hb, Lbuf, rsum);

    // fused: prep (deg/dis/wacc/CSR) interleaved with UNSCALED xw1 GEMM
    k_prep_gemm<<<9216, 256, 0, stream>>>(Lbuf, rsum, mask, dis, wacc, ents, cnts,
                                          W1T, Hb, xw1);

    // fused: CSR aggregation (y1 in LDS) + W2 GEMM + emb reduction
    k_agg_emb<<<512, 256, 0, stream>>>(ents, cnts, dis, wacc, xw1, b1, W2T, emb);

    k_final<<<B, 128, 0, stream>>>(emb, mask, b2, Wc, bc, out);
}

// Round 14
// 139.412 us; speedup vs baseline: 1.0869x; 1.0412x over previous
//
#include <hip/hip_runtime.h>
#include <hip/hip_bf16.h>
#include <math.h>

constexpr int B = 64, S = 512, D = 768, H1 = 256, H2 = 128;
constexpr float THR = 0.1f;

typedef short bf16x8 __attribute__((ext_vector_type(8)));
typedef float f32x4 __attribute__((ext_vector_type(4)));
typedef unsigned int uint_t;
typedef const __attribute__((address_space(1))) unsigned int* gptr_t;
typedef __attribute__((address_space(3))) unsigned int* lptr_t;

__device__ __forceinline__ unsigned short f2bf(float f) {
    unsigned int u = __builtin_bit_cast(unsigned int, f);
    unsigned int r = (u + 0x7FFFu + ((u >> 16) & 1u)) >> 16;
    return (unsigned short)r;
}
__device__ __forceinline__ float bf2f(unsigned short b) {
    return __builtin_bit_cast(float, (unsigned int)b << 16);
}
// fp8 e4m3fn encode (input guaranteed positive, in normal range)
__device__ __forceinline__ unsigned char f2fp8(float f) {
    uint_t u = __builtin_bit_cast(uint_t, f);
    u += 0x7FFFFu + ((u >> 20) & 1u);      // RNE to 3-bit mantissa
    return (unsigned char)((((u >> 23) - 120u) << 3) | ((u >> 20) & 7u));
}
__device__ __forceinline__ float fp82f(unsigned char q) {
    uint_t e = (q >> 3) & 0xFu, m = q & 7u;
    if (e == 0) return (float)m * 0.001953125f;   // denormal: m * 2^-9
    return __builtin_bit_cast(float, ((e + 120u) << 23) | (m << 20));
}
__device__ __forceinline__ void gl2lds16(const void* g, void* l) {
    __builtin_amdgcn_global_load_lds((gptr_t)g, (lptr_t)l, 16, 0, 0);
}

// ------- fused prologue: zero accumulators, transpose-cast W1/W2, cast H --------
__global__ __launch_bounds__(256) void k_cast(const float* __restrict__ in,
                                              short* __restrict__ out,
                                              const float* __restrict__ W1,
                                              short* __restrict__ W1T,
                                              const float* __restrict__ W2,
                                              short* __restrict__ W2T,
                                              float* __restrict__ zbuf) {
    const int id = blockIdx.x * 256 + threadIdx.x;
    if (id < 18432) ((float4*)zbuf)[id] = make_float4(0.f, 0.f, 0.f, 0.f);
    if (id < 196608) {                       // W1T[n][k] = W1[k][n]
        const int n = id / D, k = id - n * D;
        W1T[id] = (short)f2bf(W1[(size_t)k * H1 + n]);
    } else if (id < 229376) {                // W2T[n][k] = W2[k][n]
        const int i2 = id - 196608;
        const int n = i2 / H1, k = i2 - n * H1;
        W2T[i2] = (short)f2bf(W2[(size_t)k * H2 + n]);
    }
    for (int i = id; i < 3145728; i += 524288) {
        float4 a = ((const float4*)in)[i * 2];
        float4 b = ((const float4*)in)[i * 2 + 1];
        uint4 o;
        o.x = (uint_t)f2bf(a.x) | ((uint_t)f2bf(a.y) << 16);
        o.y = (uint_t)f2bf(a.z) | ((uint_t)f2bf(a.w) << 16);
        o.z = (uint_t)f2bf(b.x) | ((uint_t)f2bf(b.y) << 16);
        o.w = (uint_t)f2bf(b.z) | ((uint_t)f2bf(b.w) << 16);
        ((uint4*)out)[i] = o;
    }
}

// ---------------- logits: expL (fp8) + atomic f32 row-sums ----------------------
// Diagonal tiles (bi==bj) skip Bs staging and read B-fragments from As.
__global__ __launch_bounds__(256) void k_logits(const short* __restrict__ Hb_,
                                                unsigned char* __restrict__ L8,
                                                float* __restrict__ rsum) {
    const int orig = blockIdx.x;
    const int wg = (orig & 7) * 128 + (orig >> 3);
    const int bz = wg >> 4;
    const int bi = (wg >> 2) & 3, bj = wg & 3;
    const bool diag = (bi == bj);
    const short* Ab = Hb_ + (size_t)bz * S * D;
    unsigned char* Lb = L8 + (size_t)bz * S * S;
    float* rs = rsum + bz * S;
    const int M0 = bi * 128, N0 = bj * 128;

    __shared__ __align__(16) short As[8192];
    __shared__ __align__(16) short Bs[8192];

    const int tid = threadIdx.x, lane = tid & 63, wid = tid >> 6;
    const int wm = (wid & 1) * 64, wn = (wid >> 1) * 64;
    const int r_in = lane >> 3, kc = lane & 7;
    const int kswz = ((kc ^ r_in) << 3);

    f32x4 zero = {0.f, 0.f, 0.f, 0.f};
    f32x4 acc[4][4];
    #pragma unroll
    for (int mi = 0; mi < 4; ++mi)
        #pragma unroll
        for (int nj = 0; nj < 4; ++nj) acc[mi][nj] = zero;

    const short* Bsrc = diag ? As : Bs;

    for (int t = 0; t < 12; ++t) {
        const int kt = t * 64;
        #pragma unroll
        for (int q = 0; q < 4; ++q) {
            const int ch = wid * 4 + q;
            gl2lds16(Ab + (size_t)(M0 + ch * 8 + r_in) * D + kt + kswz, &As[ch * 512]);
        }
        if (!diag) {
            #pragma unroll
            for (int q = 0; q < 4; ++q) {
                const int ch = wid * 4 + q;
                gl2lds16(Ab + (size_t)(N0 + ch * 8 + r_in) * D + kt + kswz, &Bs[ch * 512]);
            }
        }
        __syncthreads();
        #pragma unroll
        for (int kk = 0; kk < 2; ++kk) {
            bf16x8 af[4], bfr[4];
            const int g0 = kk * 4 + (lane >> 4);
            #pragma unroll
            for (int mi = 0; mi < 4; ++mi) {
                const int row = wm + mi * 16 + (lane & 15);
                af[mi] = *(const bf16x8*)&As[row * 64 + ((g0 ^ (row & 7)) << 3)];
            }
            #pragma unroll
            for (int nj = 0; nj < 4; ++nj) {
                const int row = wn + nj * 16 + (lane & 15);
                bfr[nj] = *(const bf16x8*)&Bsrc[row * 64 + ((g0 ^ (row & 7)) << 3)];
            }
            #pragma unroll
            for (int mi = 0; mi < 4; ++mi)
                #pragma unroll
                for (int nj = 0; nj < 4; ++nj)
                    acc[mi][nj] = __builtin_amdgcn_mfma_f32_16x16x32_bf16(
                        af[mi], bfr[nj], acc[mi][nj], 0, 0, 0);
        }
        __syncthreads();
    }

    #pragma unroll
    for (int mi = 0; mi < 4; ++mi)
        #pragma unroll
        for (int nj = 0; nj < 4; ++nj) {
            f32x4 v = acc[mi][nj];
            acc[mi][nj][0] = __expf(v[0]);
            acc[mi][nj][1] = __expf(v[1]);
            acc[mi][nj][2] = __expf(v[2]);
            acc[mi][nj][3] = __expf(v[3]);
        }

    #pragma unroll
    for (int mi = 0; mi < 4; ++mi) {
        const int mb = wm + mi * 16 + (lane >> 4) * 4;
        #pragma unroll
        for (int nj = 0; nj < 4; ++nj) {
            const int n = wn + nj * 16 + (lane & 15);
            f32x4 v = acc[mi][nj];
            uchar4 o;
            o.x = f2fp8(v[0]); o.y = f2fp8(v[1]);
            o.z = f2fp8(v[2]); o.w = f2fp8(v[3]);
            *(uchar4*)&Lb[(size_t)(N0 + n) * S + M0 + mb] = o;
        }
    }

    #pragma unroll
    for (int mi = 0; mi < 4; ++mi)
        #pragma unroll
        for (int r = 0; r < 4; ++r) {
            float s = acc[mi][0][r] + acc[mi][1][r] + acc[mi][2][r] + acc[mi][3][r];
            s += __shfl_xor(s, 1); s += __shfl_xor(s, 2);
            s += __shfl_xor(s, 4); s += __shfl_xor(s, 8);
            if ((lane & 15) == 0)
                atomicAdd(&rs[M0 + wm + mi * 16 + (lane >> 4) * 4 + r], s);
        }
}

// ------- fused: prep (8/9 of blocks) + xw1 NT-GEMM (1/9 of blocks) --------------
__global__ __launch_bounds__(256) void k_prep_gemm(
    const unsigned char* __restrict__ L8, const float* __restrict__ rsum,
    const int* __restrict__ mask, float* __restrict__ dis,
    float* __restrict__ wacc, uint_t* __restrict__ ents, uint_t* __restrict__ cnts,
    const short* __restrict__ W1T, const short* __restrict__ Hb,
    short* __restrict__ xw1) {
    __shared__ __align__(16) short As[128 * 64];   // used by gemm branch only
    __shared__ __align__(16) short Bs[64 * 64];

    const int blk = blockIdx.x;
    const int r9 = blk % 9;
    const int tid = threadIdx.x, lane = tid & 63, wid = tid >> 6;

    if (r9 != 8) {
        // ---------------- prep path ----------------
        const int p = (blk / 9) * 8 + r9;            // 0..8191
        const int j = p * 4 + (tid >> 6);            // b*S + jl
        const int b = j >> 9, jl = j & (S - 1);
        const size_t base = (size_t)b * S * S + (size_t)jl * S + lane * 8;
        const uint2 r = *(const uint2*)(L8 + base);
        const int i0 = lane * 8;
        const float4 sa = *(const float4*)&rsum[b * S + i0];
        const float4 sb = *(const float4*)&rsum[b * S + i0 + 4];
        const float rsv[8] = {sa.x, sa.y, sa.z, sa.w, sb.x, sb.y, sb.z, sb.w};
        float a[8];
        float deg = 0.f;
        #pragma unroll
        for (int e = 0; e < 8; ++e) {
            const unsigned char q = (e < 4) ? (unsigned char)(r.x >> (e * 8))
                                            : (unsigned char)(r.y >> ((e - 4) * 8));
            float att = fp82f(q) / rsv[e];           // att[i][j], i = i0+e
            if (i0 + e == jl) a[e] = (att > THR) ? att : 1.0f;
            else              a[e] = (att > THR) ? att : 0.0f;
            deg += a[e];
        }
        #pragma unroll
        for (int off = 1; off < 64; off <<= 1) deg += __shfl_xor(deg, off);
        const float d = (deg > 0.f) ? rsqrtf(deg) : 0.f;
        const float cv = d * (float)mask[j];
        if (lane == 0) dis[j] = d;
        #pragma unroll
        for (int e = 0; e < 8; ++e)
            if (a[e] != 0.f) atomicAdd(&wacc[b * S + i0 + e], cv * a[e]);

        unsigned long long bl[8];
        #pragma unroll
        for (int e = 0; e < 8; ++e) bl[e] = __ballot(a[e] != 0.f);
        const unsigned long long lt = (lane == 0) ? 0ull : (~0ull >> (64 - lane));
        int pre = 0, tot = 0;
        #pragma unroll
        for (int e = 0; e < 8; ++e) {
            pre += __popcll(bl[e] & lt);
            tot += __popcll(bl[e]);
        }
        uint_t* rowents = ents + (size_t)j * S;
        int own = 0;
        #pragma unroll
        for (int e = 0; e < 8; ++e) {
            if (a[e] != 0.f) {
                rowents[pre + own] = ((uint_t)(i0 + e) << 16) | (uint_t)f2bf(a[e]);
                ++own;
            }
        }
        if (lane == 0) cnts[j] = (uint_t)tot;
        return;
    }

    // ---------------- gemm path (xw1, unscaled) ----------------
    const int orig = blk / 9;                        // 0..1023
    const int wg = (orig & 7) * 128 + (orig >> 3);   // XCD-contiguous chunks
    const int bx = wg & 1, by = wg >> 1;
    const int M0 = bx * 128, N0 = by * 64;

    const int wm = (wid & 1) * 64, wn = (wid >> 1) * 32;
    const int r_in = lane >> 3, kc = lane & 7;
    const int kswz = ((kc ^ r_in) << 3);

    f32x4 zero = {0.f, 0.f, 0.f, 0.f};
    f32x4 acc[4][2];
    #pragma unroll
    for (int mi = 0; mi < 4; ++mi) {
        acc[mi][0] = zero; acc[mi][1] = zero;
    }

    for (int t = 0; t < 12; ++t) {
        const int kt = t << 6;
        #pragma unroll
        for (int q = 0; q < 4; ++q) {
            const int ch = wid * 4 + q;
            gl2lds16(W1T + (size_t)(M0 + ch * 8 + r_in) * D + kt + kswz, &As[ch * 512]);
        }
        #pragma unroll
        for (int q = 0; q < 2; ++q) {
            const int ch = wid * 2 + q;
            gl2lds16(Hb + (size_t)(N0 + ch * 8 + r_in) * D + kt + kswz, &Bs[ch * 512]);
        }
        __syncthreads();
        #pragma unroll
        for (int kk = 0; kk < 2; ++kk) {
            bf16x8 af[4], bfr[2];
            const int g0 = kk * 4 + (lane >> 4);
            #pragma unroll
            for (int mi = 0; mi < 4; ++mi) {
                const int row = wm + mi * 16 + (lane & 15);
                af[mi] = *(const bf16x8*)&As[row * 64 + ((g0 ^ (row & 7)) << 3)];
            }
            #pragma unroll
            for (int nj = 0; nj < 2; ++nj) {
                const int row = wn + nj * 16 + (lane & 15);
                bfr[nj] = *(const bf16x8*)&Bs[row * 64 + ((g0 ^ (row & 7)) << 3)];
            }
            #pragma unroll
            for (int mi = 0; mi < 4; ++mi)
                #pragma unroll
                for (int nj = 0; nj < 2; ++nj)
                    acc[mi][nj] = __builtin_amdgcn_mfma_f32_16x16x32_bf16(
                        af[mi], bfr[nj], acc[mi][nj], 0, 0, 0);
        }
        __syncthreads();
    }

    #pragma unroll
    for (int mi = 0; mi < 4; ++mi) {
        const int m = M0 + wm + mi * 16 + (lane >> 4) * 4;
        #pragma unroll
        for (int nj = 0; nj < 2; ++nj) {
            const int n = N0 + wn + nj * 16 + (lane & 15);
            f32x4 v = acc[mi][nj];
            ushort4 o = make_ushort4(f2bf(v[0]), f2bf(v[1]), f2bf(v[2]), f2bf(v[3]));
            *(ushort4*)&xw1[(size_t)n * H1 + m] = o;
        }
    }
}

// ---------------- sparse aggregation via CSR: y1[j][h], 8 rows per block --------
// dis_i applied per entry here (xw1 is unscaled).
__global__ __launch_bounds__(256) void k_agg(const uint_t* __restrict__ ents,
                                             const uint_t* __restrict__ cnts,
                                             const float* __restrict__ dis,
                                             const short* __restrict__ xw1,
                                             const float* __restrict__ b1,
                                             short* __restrict__ y1) {
    const int tid = threadIdx.x;
    const int h = tid;
    const float bias = b1[h];
    __shared__ uint_t sents[S];
    for (int jj = 0; jj < 8; ++jj) {
        const int j = blockIdx.x * 8 + jj;
        const int b = j >> 9;
        const int cnt = (int)cnts[j];
        for (int k = tid; k < cnt; k += 256) sents[k] = ents[(size_t)j * S + k];
        __syncthreads();
        float acc = 0.f;
        for (int k = 0; k < cnt; ++k) {
            const uint_t p = sents[k];
            const int i = (int)(p >> 16);
            const float val = bf2f((unsigned short)(p & 0xFFFFu)) * dis[b * S + i];
            acc += val * bf2f((unsigned short)xw1[(size_t)(b * S + i) * H1 + h]);
        }
        const float o = fmaxf(dis[j] * acc + bias, 0.f);
        y1[(size_t)j * H1 + h] = (short)f2bf(o);
        __syncthreads();
    }
}

// ------- xw2 NT-GEMM with fused emb reduction (128 x 64 tile) -------------------
__global__ __launch_bounds__(256) void k_gemm_emb(
    const short* __restrict__ W2T, const short* __restrict__ y1,
    const float* __restrict__ wacc, const float* __restrict__ dis,
    float* __restrict__ embp) {
    const int orig = blockIdx.x;
    const int wg = (orig & 7) * 64 + (orig >> 3);
    const int N0 = wg * 64;          // token tile; M0 = 0 (H2=128 single M tile)

    __shared__ __align__(16) short As[128 * 64];
    __shared__ __align__(16) short Bs[64 * 64];

    const int tid = threadIdx.x, lane = tid & 63, wid = tid >> 6;
    const int wm = (wid & 1) * 64, wn = (wid >> 1) * 32;
    const int r_in = lane >> 3, kc = lane & 7;
    const int kswz = ((kc ^ r_in) << 3);

    f32x4 zero = {0.f, 0.f, 0.f, 0.f};
    f32x4 acc[4][2];
    #pragma unroll
    for (int mi = 0; mi < 4; ++mi) {
        acc[mi][0] = zero; acc[mi][1] = zero;
    }

    for (int t = 0; t < 4; ++t) {
        const int kt = t << 6;
        #pragma unroll
        for (int q = 0; q < 4; ++q) {
            const int ch = wid * 4 + q;
            gl2lds16(W2T + (size_t)(ch * 8 + r_in) * H1 + kt + kswz, &As[ch * 512]);
        }
        #pragma unroll
        for (int q = 0; q < 2; ++q) {
            const int ch = wid * 2 + q;
            gl2lds16(y1 + (size_t)(N0 + ch * 8 + r_in) * H1 + kt + kswz, &Bs[ch * 512]);
        }
        __syncthreads();
        #pragma unroll
        for (int kk = 0; kk < 2; ++kk) {
            bf16x8 af[4], bfr[2];
            const int g0 = kk * 4 + (lane >> 4);
            #pragma unroll
            for (int mi = 0; mi < 4; ++mi) {
                const int row = wm + mi * 16 + (lane & 15);
                af[mi] = *(const bf16x8*)&As[row * 64 + ((g0 ^ (row & 7)) << 3)];
            }
            #pragma unroll
            for (int nj = 0; nj < 2; ++nj) {
                const int row = wn + nj * 16 + (lane & 15);
                bfr[nj] = *(const bf16x8*)&Bs[row * 64 + ((g0 ^ (row & 7)) << 3)];
            }
            #pragma unroll
            for (int mi = 0; mi < 4; ++mi)
                #pragma unroll
                for (int nj = 0; nj < 2; ++nj)
                    acc[mi][nj] = __builtin_amdgcn_mfma_f32_16x16x32_bf16(
                        af[mi], bfr[nj], acc[mi][nj], 0, 0, 0);
        }
        __syncthreads();
    }

    const int bb = N0 >> 9;
    float wv[2];
    #pragma unroll
    for (int nj = 0; nj < 2; ++nj) {
        const int gn = N0 + wn + nj * 16 + (lane & 15);
        wv[nj] = wacc[gn] * dis[gn];
    }
    #pragma unroll
    for (int mi = 0; mi < 4; ++mi)
        #pragma unroll
        for (int r = 0; r < 4; ++r) {
            float s = acc[mi][0][r] * wv[0] + acc[mi][1][r] * wv[1];
            s += __shfl_xor(s, 1); s += __shfl_xor(s, 2);
            s += __shfl_xor(s, 4); s += __shfl_xor(s, 8);
            if ((lane & 15) == 0) {
                const int h = wm + mi * 16 + (lane >> 4) * 4 + r;
                atomicAdd(&embp[bb * H2 + h], s);
            }
        }
}

// ---------------- final: head from emb[64][128] ---------------------------------
__global__ __launch_bounds__(128) void k_final(const float* __restrict__ emb,
                                               const int* __restrict__ mask,
                                               const float* __restrict__ b2,
                                               const float* __restrict__ Wc,
                                               const float* __restrict__ bc,
                                               float* __restrict__ out) {
    const int b = blockIdx.x;
    const int h = threadIdx.x;
    const int* mb = mask + b * S;

    float msum = 0.f;
    for (int i = h; i < S; i += 128) msum += (float)mb[i];
    #pragma unroll
    for (int off = 1; off < 64; off <<= 1) msum += __shfl_xor(msum, off);
    __shared__ float redm[2], redv[2];
    if ((h & 63) == 0) redm[h >> 6] = msum;
    __syncthreads();
    msum = redm[0] + redm[1];

    const float e = b2[h] + emb[b * H2 + h] / msum;
    float val = e * Wc[h];
    #pragma unroll
    for (int off = 1; off < 64; off <<= 1) val += __shfl_xor(val, off);
    if ((h & 63) == 0) redv[h >> 6] = val;
    __syncthreads();
    if (h == 0) {
        float z = redv[0] + redv[1] + bc[0];
        out[b] = 1.f / (1.f + expf(-z));
    }
}

extern "C" void kernel_launch(void* const* d_in, const int* in_sizes, int n_in,
                              void* d_out, int out_size, void* d_ws, size_t ws_size,
                              hipStream_t stream) {
    const float* H    = (const float*)d_in[0];
    const int*   mask = (const int*)d_in[1];
    const float* W1   = (const float*)d_in[2];
    const float* b1   = (const float*)d_in[3];
    const float* W2   = (const float*)d_in[4];
    const float* b2   = (const float*)d_in[5];
    const float* Wc   = (const float*)d_in[6];
    const float* bc   = (const float*)d_in[7];
    float* out = (float*)d_out;

    const int NTOK = B * S;  // 32768

    // workspace layout (bytes)
    char* wsb = (char*)d_ws;
    short* Hb    = (short*)(wsb);                       // 48 MB
    short* y1    = (short*)(wsb);                       // overlays Hb (dead by then)
    unsigned char* Lbuf = (unsigned char*)(wsb + 50331648);  // 16 MB fp8
    short* xw1   = (short*)(wsb + 83886080);            // 16 MB, [tok][H1]
    float* rsum  = (float*)(wsb + 109051904);           // 32768 f
    float* wacc  = rsum + NTOK;                         // 32768 f
    float* emb   = wacc + NTOK;                         // 8192 f (zeroed with rsum/wacc)
    float* dis   = emb + 8192;                          // 32768 f
    short* W1T   = (short*)(dis + NTOK);                // 196608 el
    short* W2T   = W1T + 196608;                        // 32768 el
    uint_t* ents = (uint_t*)(wsb + 134217728);          // 64 MB
    uint_t* cnts = (uint_t*)(wsb + 201326592);          // 32768 u32

    // prologue: zero rsum+wacc+emb, cast weights (transposed), cast H
    k_cast<<<2048, 256, 0, stream>>>(H, Hb, W1, W1T, W2, W2T, rsum);

    // expL fp8 (full grid, XCD swizzle, swizzled LDS, diag staging dedup) + row sums
    k_logits<<<1024, 256, 0, stream>>>(Hb, Lbuf, rsum);

    // fused: prep (deg/dis/wacc/CSR) interleaved with UNSCALED xw1 GEMM
    k_prep_gemm<<<9216, 256, 0, stream>>>(Lbuf, rsum, mask, dis, wacc, ents, cnts,
                                          W1T, Hb, xw1);

    // sparse aggregation + relu + bias (CSR-driven, dis_i applied per entry)
    k_agg<<<4096, 256, 0, stream>>>(ents, cnts, dis, xw1, b1, y1);

    // emb[b][h2] += sum_t (y1 @ W2)[t][h2] * wacc[t]*dis[t]
    k_gemm_emb<<<512, 256, 0, stream>>>(W2T, y1, wacc, dis, emb);

    k_final<<<B, 128, 0, stream>>>(emb, mask, b2, Wc, bc, out);
}